// Round 1
// baseline (235.600 us; speedup 1.0000x reference)
//
#include <hip/hip_runtime.h>

// SoftNormalShader: fused normal_shading + softmax_rgb_blend
// N=4, H=512, W=512, K=8, V=50000, F=100000
// Inputs (fp32 unless noted):
//  d_in[0] verts_normals (V,3)
//  d_in[1] bary_coords   (N,H,W,K,3)
//  d_in[2] dists         (N,H,W,K)
//  d_in[3] zbuf          (N,H,W,K)
//  d_in[4] faces         (F,3)  int32
//  d_in[5] pix_to_face   (N,H,W,K) int32  (-1 = background)
// Output: (N,H,W,4) fp32

constexpr int   N_PIX      = 4 * 512 * 512;
constexpr float INV_SIGMA  = 1.0f / 1e-4f;
constexpr float INV_GAMMA  = 1.0f / 1e-4f;
constexpr float ZFARV      = 100.0f;
constexpr float INV_ZRANGE = 1.0f / 99.0f;   // 1/(ZFAR-ZNEAR)
constexpr float EPSV       = 1e-10f;

// Prepass: pack gathered vertex normals per face into a 48B row
// (L2-resident 4.8MB table) so the hot kernel does 3x dwordx4 gathers
// instead of 12x dword gathers per fragment.
__global__ __launch_bounds__(256)
void build_face_normals_kernel(const float* __restrict__ vn,
                               const int*   __restrict__ faces,
                               float*       __restrict__ fn,
                               int nf)
{
    int f = blockIdx.x * blockDim.x + threadIdx.x;
    if (f >= nf) return;
    int v0 = faces[3 * f + 0];
    int v1 = faces[3 * f + 1];
    int v2 = faces[3 * f + 2];
    const float* p0 = vn + 3 * (size_t)v0;
    const float* p1 = vn + 3 * (size_t)v1;
    const float* p2 = vn + 3 * (size_t)v2;
    float4 r0 = make_float4(p0[0], p0[1], p0[2], p1[0]);
    float4 r1 = make_float4(p1[1], p1[2], p2[0], p2[1]);
    float4 r2 = make_float4(p2[2], 0.f, 0.f, 0.f);
    float4* dst = reinterpret_cast<float4*>(fn + 12 * (size_t)f);
    dst[0] = r0; dst[1] = r1; dst[2] = r2;
}

__global__ __launch_bounds__(256)
void shade_kernel(const float* __restrict__ bary,
                  const float* __restrict__ dists,
                  const float* __restrict__ zbuf,
                  const int*   __restrict__ p2f,
                  const float* __restrict__ fn,     // packed table (or null)
                  const float* __restrict__ vn,     // fallback direct-gather path
                  const int*   __restrict__ faces,  // fallback direct-gather path
                  float*       __restrict__ out)
{
    int pix = blockIdx.x * blockDim.x + threadIdx.x;
    if (pix >= N_PIX) return;

    // Streaming loads, fully vectorized (per-thread contiguous: 96B bary,
    // 32B each of dists/zbuf/p2f).
    const float4* dptr = reinterpret_cast<const float4*>(dists + 8 * (size_t)pix);
    const float4* zptr = reinterpret_cast<const float4*>(zbuf  + 8 * (size_t)pix);
    const int4*   fptr = reinterpret_cast<const int4*>(p2f     + 8 * (size_t)pix);
    const float4* bptr = reinterpret_cast<const float4*>(bary  + 24 * (size_t)pix);

    float4 d0 = dptr[0], d1 = dptr[1];
    float4 z0 = zptr[0], z1 = zptr[1];
    int4   f0 = fptr[0], f1 = fptr[1];
    float4 b0 = bptr[0], b1 = bptr[1], b2 = bptr[2];
    float4 b3 = bptr[3], b4 = bptr[4], b5 = bptr[5];

    float dk[8] = {d0.x, d0.y, d0.z, d0.w, d1.x, d1.y, d1.z, d1.w};
    float zk[8] = {z0.x, z0.y, z0.z, z0.w, z1.x, z1.y, z1.z, z1.w};
    int   fk[8] = {f0.x, f0.y, f0.z, f0.w, f1.x, f1.y, f1.z, f1.w};
    float bf[24] = {b0.x, b0.y, b0.z, b0.w, b1.x, b1.y, b1.z, b1.w,
                    b2.x, b2.y, b2.z, b2.w, b3.x, b3.y, b3.z, b3.w,
                    b4.x, b4.y, b4.z, b4.w, b5.x, b5.y, b5.z, b5.w};

    // Pass 1: sigmoid prob, z_inv, running alpha and z_inv_max.
    float prob[8], zinv[8];
    float zmax  = 0.0f;   // all z_inv values are >= 0 (masked entries are 0)
    float alpha = 1.0f;
#pragma unroll
    for (int k = 0; k < 8; ++k) {
        bool  m  = fk[k] >= 0;
        // sigmoid(-d/sigma) = 1/(1+exp(d/sigma))
        float pr = m ? __builtin_amdgcn_rcpf(1.0f + __expf(dk[k] * INV_SIGMA)) : 0.0f;
        prob[k]  = pr;
        alpha   *= (1.0f - pr);
        float zi = m ? (ZFARV - zk[k]) * INV_ZRANGE : 0.0f;
        zinv[k]  = zi;
        zmax     = fmaxf(zmax, zi);
    }

    // Pass 2: softmax weights + gather/interp only where weight != 0.
    // exp((zinv-zmax)/GAMMA) underflows to exactly 0 unless zinv is within
    // ~0.0087 of zmax, so typically only ~1 of 8 fragments gathers.
    float wsum = 0.0f, cr = 0.0f, cg = 0.0f, cb = 0.0f;
#pragma unroll
    for (int k = 0; k < 8; ++k) {
        float w = prob[k] * __expf((zinv[k] - zmax) * INV_GAMMA);
        if (w != 0.0f) {
            int idx = fk[k] < 0 ? 0 : fk[k];
            float n0x, n0y, n0z, n1x, n1y, n1z, n2x, n2y, n2z;
            if (fn) {
                const float4* fr = reinterpret_cast<const float4*>(fn + 12 * (size_t)idx);
                float4 r0 = fr[0], r1 = fr[1], r2 = fr[2];
                n0x = r0.x; n0y = r0.y; n0z = r0.z;
                n1x = r0.w; n1y = r1.x; n1z = r1.y;
                n2x = r1.z; n2y = r1.w; n2z = r2.x;
            } else {
                int v0 = faces[3 * idx + 0];
                int v1 = faces[3 * idx + 1];
                int v2 = faces[3 * idx + 2];
                n0x = vn[3 * v0 + 0]; n0y = vn[3 * v0 + 1]; n0z = vn[3 * v0 + 2];
                n1x = vn[3 * v1 + 0]; n1y = vn[3 * v1 + 1]; n1z = vn[3 * v1 + 2];
                n2x = vn[3 * v2 + 0]; n2y = vn[3 * v2 + 1]; n2z = vn[3 * v2 + 2];
            }
            float bw0 = bf[3 * k + 0], bw1 = bf[3 * k + 1], bw2 = bf[3 * k + 2];
            cr += w * (bw0 * n0x + bw1 * n1x + bw2 * n2x);
            cg += w * (bw0 * n0y + bw1 * n1y + bw2 * n2y);
            cb += w * (bw0 * n0z + bw1 * n1z + bw2 * n2z);
        }
        wsum += w;
    }

    float delta     = fmaxf(__expf((EPSV - zmax) * INV_GAMMA), EPSV);
    float inv_denom = 1.0f / (wsum + delta);

    float4 o;
    o.x = (cr + delta) * inv_denom;   // background = (1,1,1)
    o.y = (cg + delta) * inv_denom;
    o.z = (cb + delta) * inv_denom;
    o.w = 1.0f - alpha;
    reinterpret_cast<float4*>(out)[pix] = o;
}

extern "C" void kernel_launch(void* const* d_in, const int* in_sizes, int n_in,
                              void* d_out, int out_size, void* d_ws, size_t ws_size,
                              hipStream_t stream) {
    const float* vn    = (const float*)d_in[0];
    const float* bary  = (const float*)d_in[1];
    const float* dists = (const float*)d_in[2];
    const float* zbuf  = (const float*)d_in[3];
    const int*   faces = (const int*)d_in[4];
    const int*   p2f   = (const int*)d_in[5];
    float*       out   = (float*)d_out;

    int nf = in_sizes[4] / 3;

    float* fn = nullptr;
    size_t need = (size_t)nf * 12 * sizeof(float);
    if (ws_size >= need) {
        fn = (float*)d_ws;
        build_face_normals_kernel<<<(nf + 255) / 256, 256, 0, stream>>>(vn, faces, fn, nf);
    }

    shade_kernel<<<N_PIX / 256, 256, 0, stream>>>(bary, dists, zbuf, p2f,
                                                  fn, vn, faces, out);
}

// Round 2
// 228.223 us; speedup vs baseline: 1.0323x; 1.0323x over previous
//
#include <hip/hip_runtime.h>

// SoftNormalShader: fused normal_shading + softmax_rgb_blend
// Layout R2: one lane per (pixel, fragment-k). All streaming loads are
// perfectly coalesced; per-pixel reductions are 8-lane shfl_xor butterflies.
// N=4, H=512, W=512, K=8, V=50000, F=100000

constexpr int   N_PIX      = 4 * 512 * 512;
constexpr int   N_FRAG     = N_PIX * 8;
constexpr float INV_SIGMA  = 1.0f / 1e-4f;
constexpr float INV_GAMMA  = 1.0f / 1e-4f;
constexpr float ZFARV      = 100.0f;
constexpr float INV_ZRANGE = 1.0f / 99.0f;   // 1/(ZFAR-ZNEAR)
constexpr float EPSV       = 1e-10f;

// Prepass: pack gathered vertex normals per face into a 48B row
// (4.8MB table, L2/L3-resident) so the hot kernel does 3x dwordx4 gathers
// instead of 12x dword gathers per active fragment.
__global__ __launch_bounds__(256)
void build_face_normals_kernel(const float* __restrict__ vn,
                               const int*   __restrict__ faces,
                               float*       __restrict__ fn,
                               int nf)
{
    int f = blockIdx.x * blockDim.x + threadIdx.x;
    if (f >= nf) return;
    int v0 = faces[3 * f + 0];
    int v1 = faces[3 * f + 1];
    int v2 = faces[3 * f + 2];
    const float* p0 = vn + 3 * (size_t)v0;
    const float* p1 = vn + 3 * (size_t)v1;
    const float* p2 = vn + 3 * (size_t)v2;
    float4 r0 = make_float4(p0[0], p0[1], p0[2], p1[0]);
    float4 r1 = make_float4(p1[1], p1[2], p2[0], p2[1]);
    float4 r2 = make_float4(p2[2], 0.f, 0.f, 0.f);
    float4* dst = reinterpret_cast<float4*>(fn + 12 * (size_t)f);
    dst[0] = r0; dst[1] = r1; dst[2] = r2;
}

__global__ __launch_bounds__(256)
void shade_kernel(const float* __restrict__ bary,
                  const float* __restrict__ dists,
                  const float* __restrict__ zbuf,
                  const int*   __restrict__ p2f,
                  const float* __restrict__ fn,     // packed table (or null)
                  const float* __restrict__ vn,     // fallback path
                  const int*   __restrict__ faces,  // fallback path
                  float*       __restrict__ out)
{
    int gid = blockIdx.x * blockDim.x + threadIdx.x;   // fragment id
    if (gid >= N_FRAG) return;
    int kk  = gid & 7;                                  // fragment index in pixel
    int pix = gid >> 3;

    // Perfectly coalesced streaming loads (4B/lane, dense across wave).
    float d  = dists[gid];
    float zb = zbuf[gid];
    int   f  = p2f[gid];

    bool  m  = f >= 0;
    // sigmoid(-d/sigma) = 1/(1+exp(d/sigma))
    float pr = m ? __builtin_amdgcn_rcpf(1.0f + __expf(d * INV_SIGMA)) : 0.0f;
    float zi = m ? (ZFARV - zb) * INV_ZRANGE : 0.0f;

    // 8-lane butterfly reductions (masks 1,2,4 stay inside the k-group).
    float zmax = zi;
    zmax = fmaxf(zmax, __shfl_xor(zmax, 1));
    zmax = fmaxf(zmax, __shfl_xor(zmax, 2));
    zmax = fmaxf(zmax, __shfl_xor(zmax, 4));

    float am = 1.0f - pr;           // alpha = prod(1 - prob)
    am *= __shfl_xor(am, 1);
    am *= __shfl_xor(am, 2);
    am *= __shfl_xor(am, 4);

    // Softmax weight; exp underflows to exactly 0 unless zi is within
    // ~0.0087 of zmax -> typically ~1 of 8 lanes gathers.
    float w = pr * __expf((zi - zmax) * INV_GAMMA);

    float cr = 0.0f, cg = 0.0f, cb = 0.0f;
    if (w != 0.0f) {                 // implies m, so f >= 0
        // bary only needed for contributing fragments.
        float b0 = bary[3 * (size_t)gid + 0];
        float b1 = bary[3 * (size_t)gid + 1];
        float b2 = bary[3 * (size_t)gid + 2];
        float n0x, n0y, n0z, n1x, n1y, n1z, n2x, n2y, n2z;
        if (fn) {
            const float4* fr = reinterpret_cast<const float4*>(fn + 12 * (size_t)f);
            float4 r0 = fr[0], r1 = fr[1], r2 = fr[2];
            n0x = r0.x; n0y = r0.y; n0z = r0.z;
            n1x = r0.w; n1y = r1.x; n1z = r1.y;
            n2x = r1.z; n2y = r1.w; n2z = r2.x;
        } else {
            int v0 = faces[3 * f + 0];
            int v1 = faces[3 * f + 1];
            int v2 = faces[3 * f + 2];
            n0x = vn[3 * v0 + 0]; n0y = vn[3 * v0 + 1]; n0z = vn[3 * v0 + 2];
            n1x = vn[3 * v1 + 0]; n1y = vn[3 * v1 + 1]; n1z = vn[3 * v1 + 2];
            n2x = vn[3 * v2 + 0]; n2y = vn[3 * v2 + 1]; n2z = vn[3 * v2 + 2];
        }
        cr = w * (b0 * n0x + b1 * n1x + b2 * n2x);
        cg = w * (b0 * n0y + b1 * n1y + b2 * n2y);
        cb = w * (b0 * n0z + b1 * n1z + b2 * n2z);
    }

    // Sum reductions over the 8-lane group.
    float ws = w;
    ws += __shfl_xor(ws, 1);  cr += __shfl_xor(cr, 1);
    cg += __shfl_xor(cg, 1);  cb += __shfl_xor(cb, 1);
    ws += __shfl_xor(ws, 2);  cr += __shfl_xor(cr, 2);
    cg += __shfl_xor(cg, 2);  cb += __shfl_xor(cb, 2);
    ws += __shfl_xor(ws, 4);  cr += __shfl_xor(cr, 4);
    cg += __shfl_xor(cg, 4);  cb += __shfl_xor(cb, 4);

    if (kk == 0) {
        float delta     = fmaxf(__expf((EPSV - zmax) * INV_GAMMA), EPSV);
        float inv_denom = __builtin_amdgcn_rcpf(ws + delta);
        float4 o;
        o.x = (cr + delta) * inv_denom;   // background = (1,1,1)
        o.y = (cg + delta) * inv_denom;
        o.z = (cb + delta) * inv_denom;
        o.w = 1.0f - am;
        // 8 storing lanes per wave write contiguous float4s -> coalesced 128B.
        reinterpret_cast<float4*>(out)[pix] = o;
    }
}

extern "C" void kernel_launch(void* const* d_in, const int* in_sizes, int n_in,
                              void* d_out, int out_size, void* d_ws, size_t ws_size,
                              hipStream_t stream) {
    const float* vn    = (const float*)d_in[0];
    const float* bary  = (const float*)d_in[1];
    const float* dists = (const float*)d_in[2];
    const float* zbuf  = (const float*)d_in[3];
    const int*   faces = (const int*)d_in[4];
    const int*   p2f   = (const int*)d_in[5];
    float*       out   = (float*)d_out;

    int nf = in_sizes[4] / 3;

    float* fn = nullptr;
    size_t need = (size_t)nf * 12 * sizeof(float);
    if (ws_size >= need) {
        fn = (float*)d_ws;
        build_face_normals_kernel<<<(nf + 255) / 256, 256, 0, stream>>>(vn, faces, fn, nf);
    }

    shade_kernel<<<N_FRAG / 256, 256, 0, stream>>>(bary, dists, zbuf, p2f,
                                                   fn, vn, faces, out);
}